// Round 1
// baseline (92.375 us; speedup 1.0000x reference)
//
#include <hip/hip_runtime.h>
#include <float.h>

// NearestCluster: per-batch NN argmin.
// coords1 [L1=4096, N=8, C=3] f32 (reference points)
// coords2 [L2=4096, N=8, C=3] f32 (query points)
// out int32: [L2*N] cluster idx (argmin over L1, per batch), then [L2*N] batch idx.
//
// Numerics: bit-exact replication of numpy f32 reference:
//   qq = (q0*q0 + q1*q1) + q2*q2          (round each op, no fma)
//   rr = (r0*r0 + r1*r1) + r2*r2
//   dot = ((q0*r0) + (q1*r1)) + (q2*r2)   (round each op, no fma)
//   d2 = (qq + rr) - 2*dot                (2*dot exact; single-round subtract
//                                          == __fmaf_rn(-2, dot, qq+rr))
// argmin ties -> lowest index (np.argmin first occurrence).

typedef float v2f __attribute__((ext_vector_type(2)));

constexpr int kL1 = 4096, kL2 = 4096, kN = 8;

__global__ __launch_bounds__(256, 2)
void nearest_kernel(const float* __restrict__ c1, const float* __restrict__ c2,
                    int* __restrict__ out) {
#pragma clang fp contract(off)
  // x, y, z, rr per reference point for this batch. 64 KB -> 2 blocks/CU.
  __shared__ float4 refs[kL1];

  const int tid = threadIdx.x;
  const int n = blockIdx.y;

  // ---- Stage coords1[:, n, :] into LDS, precompute rr with np rounding ----
#pragma unroll
  for (int k = 0; k < kL1 / 256; ++k) {
    const int j = tid + 256 * k;
    const float* p = c1 + (j * kN + n) * 3;  // stride 96B gather, L2-resident
    const float r0 = p[0], r1 = p[1], r2 = p[2];
    const float rr = __fadd_rn(
        __fadd_rn(__fmul_rn(r0, r0), __fmul_rn(r1, r1)), __fmul_rn(r2, r2));
    refs[j] = make_float4(r0, r1, r2, rr);
  }

  // ---- Each group of 8 lanes handles 2 queries; refs split j = lane8 (mod 8) ----
  const int g = tid >> 3;       // 0..31
  const int lane8 = tid & 7;    // 0..7
  const int qa = blockIdx.x * 64 + g * 2;  // query a
  const int qb = qa + 1;                   // query b

  const float* pa = c2 + (qa * kN + n) * 3;
  const float* pb = c2 + (qb * kN + n) * 3;
  const v2f qx = {pa[0], pb[0]};
  const v2f qy = {pa[1], pb[1]};
  const v2f qz = {pa[2], pb[2]};
  const v2f qq = {
      __fadd_rn(__fadd_rn(__fmul_rn(qx.x, qx.x), __fmul_rn(qy.x, qy.x)),
                __fmul_rn(qz.x, qz.x)),
      __fadd_rn(__fadd_rn(__fmul_rn(qx.y, qx.y), __fmul_rn(qy.y, qy.y)),
                __fmul_rn(qz.y, qz.y))};

  __syncthreads();

  // Two accumulators per query (even/odd 8-strides) to break the cmp->cndmask chain.
  v2f bd0 = {FLT_MAX, FLT_MAX}, bd1 = {FLT_MAX, FLT_MAX};
  int bi0a = 0, bi0b = 0, bi1a = 0, bi1b = 0;

#pragma unroll 2
  for (int t = 0; t < kL1 / 16; ++t) {
    const int j0 = lane8 + 16 * t;
    const float4 rA = refs[j0];
    const float4 rB = refs[j0 + 8];
    {
      const v2f m0 = qx * rA.x;
      const v2f m1 = qy * rA.y;
      const v2f s01 = m0 + m1;
      const v2f m2 = qz * rA.z;
      const v2f dot = s01 + m2;
      const v2f A = qq + rA.w;
      const float da = __fmaf_rn(-2.0f, dot.x, A.x);
      const float db = __fmaf_rn(-2.0f, dot.y, A.y);
      if (da < bd0.x) { bd0.x = da; bi0a = j0; }
      if (db < bd0.y) { bd0.y = db; bi0b = j0; }
    }
    {
      const v2f m0 = qx * rB.x;
      const v2f m1 = qy * rB.y;
      const v2f s01 = m0 + m1;
      const v2f m2 = qz * rB.z;
      const v2f dot = s01 + m2;
      const v2f A = qq + rB.w;
      const float da = __fmaf_rn(-2.0f, dot.x, A.x);
      const float db = __fmaf_rn(-2.0f, dot.y, A.y);
      if (da < bd1.x) { bd1.x = da; bi1a = j0 + 8; }
      if (db < bd1.y) { bd1.y = db; bi1b = j0 + 8; }
    }
  }

  // ---- In-thread merge (tie -> lower index) ----
  float bda = bd0.x; int bia = bi0a;
  if (bd1.x < bda || (bd1.x == bda && bi1a < bia)) { bda = bd1.x; bia = bi1a; }
  float bdb = bd0.y; int bib = bi0b;
  if (bd1.y < bdb || (bd1.y == bdb && bi1b < bib)) { bdb = bd1.y; bib = bi1b; }

  // ---- Cross-lane merge over the 8-lane group (xor 1,2,4) ----
#pragma unroll
  for (int m = 1; m <= 4; m <<= 1) {
    const float oda = __shfl_xor(bda, m);
    const int oia = __shfl_xor(bia, m);
    if (oda < bda || (oda == bda && oia < bia)) { bda = oda; bia = oia; }
    const float odb = __shfl_xor(bdb, m);
    const int oib = __shfl_xor(bib, m);
    if (odb < bdb || (odb == bdb && oib < bib)) { bdb = odb; bib = oib; }
  }

  if (lane8 == 0) {
    out[qa * kN + n] = bia;
    out[qb * kN + n] = bib;
    out[kL2 * kN + qa * kN + n] = n;
    out[kL2 * kN + qb * kN + n] = n;
  }
}

extern "C" void kernel_launch(void* const* d_in, const int* in_sizes, int n_in,
                              void* d_out, int out_size, void* d_ws, size_t ws_size,
                              hipStream_t stream) {
  const float* c1 = (const float*)d_in[0];
  const float* c2 = (const float*)d_in[1];
  int* out = (int*)d_out;
  dim3 grid(kL2 / 64, kN);
  nearest_kernel<<<grid, dim3(256), 0, stream>>>(c1, c2, out);
}

// Round 2
// 89.337 us; speedup vs baseline: 1.0340x; 1.0340x over previous
//
#include <hip/hip_runtime.h>
#include <float.h>

// NearestCluster: per-batch NN argmin.
// coords1 [L1=4096, N=8, C=3] f32 (reference points)
// coords2 [L2=4096, N=8, C=3] f32 (query points)
// out int32: [L2*N] cluster idx (argmin over L1, per batch), then [L2*N] batch idx.
//
// Numerics: bit-exact replication of numpy f32 reference:
//   qq = (q0*q0 + q1*q1) + q2*q2          (round each op, no fma)
//   rr = (r0*r0 + r1*r1) + r2*r2
//   dot = ((q0*r0) + (q1*r1)) + (q2*r2)   (round each op, no fma)
//   d2 = (qq + rr) - 2*dot                (2*dot exact; single-round subtract
//                                          == __fmaf_rn(-2, dot, qq+rr))
// argmin ties -> lowest index (np.argmin first occurrence).
//
// R1: 32 KB LDS chunks (2 passes) -> 4 blocks/CU, 16 waves/CU, grid 1024.
//     R0 was 64 KB LDS, 2 blocks/CU, Occupancy 17%, VALUBusy 58% (latency-bound).

typedef float v2f __attribute__((ext_vector_type(2)));

constexpr int kL1 = 4096, kL2 = 4096, kN = 8;
constexpr int kChunk = 2048;      // refs per LDS chunk -> 32 KB
constexpr int kQPerBlock = 32;    // 16 groups of 16 lanes x 2 queries

__global__ __launch_bounds__(256, 4)
void nearest_kernel(const float* __restrict__ c1, const float* __restrict__ c2,
                    int* __restrict__ out) {
#pragma clang fp contract(off)
  __shared__ float4 refs[kChunk];  // x, y, z, rr

  const int tid = threadIdx.x;
  const int n = blockIdx.y;

  // ---- 16-lane groups; 2 queries per group ----
  const int g = tid >> 4;        // 0..15
  const int lane16 = tid & 15;   // 0..15
  const int qa = blockIdx.x * kQPerBlock + g * 2;
  const int qb = qa + 1;

  const float* pa = c2 + (qa * kN + n) * 3;
  const float* pb = c2 + (qb * kN + n) * 3;
  const v2f qx = {pa[0], pb[0]};
  const v2f qy = {pa[1], pb[1]};
  const v2f qz = {pa[2], pb[2]};
  const v2f qq = {
      __fadd_rn(__fadd_rn(__fmul_rn(qx.x, qx.x), __fmul_rn(qy.x, qy.x)),
                __fmul_rn(qz.x, qz.x)),
      __fadd_rn(__fadd_rn(__fmul_rn(qx.y, qx.y), __fmul_rn(qy.y, qy.y)),
                __fmul_rn(qz.y, qz.y))};

  // Two accumulators per query (j0 vs j0+16 strides) for ILP.
  v2f bd0 = {FLT_MAX, FLT_MAX}, bd1 = {FLT_MAX, FLT_MAX};
  int bi0a = 0, bi0b = 0, bi1a = 0, bi1b = 0;

  for (int chunk = 0; chunk < kL1 / kChunk; ++chunk) {
    __syncthreads();  // previous chunk's readers done before overwrite

    // ---- Stage chunk of coords1[:, n, :] into LDS with np-rounded rr ----
#pragma unroll
    for (int k = 0; k < kChunk / 256; ++k) {
      const int j = tid + 256 * k;
      const float* p = c1 + ((chunk * kChunk + j) * kN + n) * 3;
      const float r0 = p[0], r1 = p[1], r2 = p[2];
      const float rr = __fadd_rn(
          __fadd_rn(__fmul_rn(r0, r0), __fmul_rn(r1, r1)), __fmul_rn(r2, r2));
      refs[j] = make_float4(r0, r1, r2, rr);
    }
    __syncthreads();

    const int base = chunk * kChunk;
#pragma unroll 2
    for (int t = 0; t < kChunk / 32; ++t) {  // 64 iters/chunk
      const int j0 = lane16 + 32 * t;
      const float4 rA = refs[j0];
      const float4 rB = refs[j0 + 16];
      {
        const v2f m0 = qx * rA.x;
        const v2f m1 = qy * rA.y;
        const v2f s01 = m0 + m1;
        const v2f m2 = qz * rA.z;
        const v2f dot = s01 + m2;
        const v2f A = qq + rA.w;
        const float da = __fmaf_rn(-2.0f, dot.x, A.x);
        const float db = __fmaf_rn(-2.0f, dot.y, A.y);
        if (da < bd0.x) { bd0.x = da; bi0a = base + j0; }
        if (db < bd0.y) { bd0.y = db; bi0b = base + j0; }
      }
      {
        const v2f m0 = qx * rB.x;
        const v2f m1 = qy * rB.y;
        const v2f s01 = m0 + m1;
        const v2f m2 = qz * rB.z;
        const v2f dot = s01 + m2;
        const v2f A = qq + rB.w;
        const float da = __fmaf_rn(-2.0f, dot.x, A.x);
        const float db = __fmaf_rn(-2.0f, dot.y, A.y);
        if (da < bd1.x) { bd1.x = da; bi1a = base + j0 + 16; }
        if (db < bd1.y) { bd1.y = db; bi1b = base + j0 + 16; }
      }
    }
  }

  // ---- In-thread merge (tie -> lower index; bd0 indices < bd1 within chunk,
  //      but across chunks ordering isn't guaranteed -> index-aware) ----
  float bda = bd0.x; int bia = bi0a;
  if (bd1.x < bda || (bd1.x == bda && bi1a < bia)) { bda = bd1.x; bia = bi1a; }
  float bdb = bd0.y; int bib = bi0b;
  if (bd1.y < bdb || (bd1.y == bdb && bi1b < bib)) { bdb = bd1.y; bib = bi1b; }

  // ---- Cross-lane merge over the 16-lane group (xor 1,2,4,8) ----
#pragma unroll
  for (int m = 1; m <= 8; m <<= 1) {
    const float oda = __shfl_xor(bda, m);
    const int oia = __shfl_xor(bia, m);
    if (oda < bda || (oda == bda && oia < bia)) { bda = oda; bia = oia; }
    const float odb = __shfl_xor(bdb, m);
    const int oib = __shfl_xor(bib, m);
    if (odb < bdb || (odb == bdb && oib < bib)) { bdb = odb; bib = oib; }
  }

  if (lane16 == 0) {
    out[qa * kN + n] = bia;
    out[qb * kN + n] = bib;
    out[kL2 * kN + qa * kN + n] = n;
    out[kL2 * kN + qb * kN + n] = n;
  }
}

extern "C" void kernel_launch(void* const* d_in, const int* in_sizes, int n_in,
                              void* d_out, int out_size, void* d_ws, size_t ws_size,
                              hipStream_t stream) {
  const float* c1 = (const float*)d_in[0];
  const float* c2 = (const float*)d_in[1];
  int* out = (int*)d_out;
  dim3 grid(kL2 / kQPerBlock, kN);  // 128 x 8 = 1024 blocks
  nearest_kernel<<<grid, dim3(256), 0, stream>>>(c1, c2, out);
}